// Round 2
// baseline (69.044 us; speedup 1.0000x reference)
//
#include <hip/hip_runtime.h>

#define BB 8
#define HH 64
#define WW 2048
#define NC 20

// tile: 4 rows x 64 cols per 256-thread block
// depth halo = 4 (9x9 neighborhood, 0.0-padded = exact reference unfold pad)
// label halo = 2 (5x5 neighborhood, 0-padded = exact reference unfold pad)

__global__ __launch_bounds__(256, 2) void knn_refine(
    const float* __restrict__ depth,
    const int*   __restrict__ label,
    const float* __restrict__ wker,
    int*         __restrict__ out)
{
    __shared__ float sD[12][72];
    __shared__ int   sL[8][68];

    const int b  = blockIdx.z;
    const int y0 = blockIdx.y * 4;
    const int x0 = blockIdx.x * 64;
    const int t  = threadIdx.x;

    const float* Db = depth + (size_t)b * (HH * WW);
    const int*   Lb = label + (size_t)b * (HH * WW);

    // ---- stage depth tile (+4 halo), OOB pad = 0.0 (matches unfold zero-pad:
    //      |0 - Dq| = Dq, exactly the reference's padded-neighbor jump) ----
    for (int idx = t; idx < 12 * 72; idx += 256) {
        int ry = idx / 72, rx = idx - ry * 72;
        int gy = y0 + ry - 4, gx = x0 + rx - 4;
        float v = 0.0f;
        if (gy >= 0 && gy < HH && gx >= 0 && gx < WW) v = Db[gy * WW + gx];
        sD[ry][rx] = v;
    }
    // ---- stage label tile (+2 halo), OOB pad = 0 ----
    for (int idx = t; idx < 8 * 68; idx += 256) {
        int ry = idx / 68, rx = idx - ry * 68;
        int gy = y0 + ry - 2, gx = x0 + rx - 2;
        int v = 0;
        if (gy >= 0 && gy < HH && gx >= 0 && gx < WW) v = Lb[gy * WW + gx];
        sL[ry][rx] = v;
    }
    __syncthreads();

    const int px = t & 63;
    const int py = t >> 6;
    const int gy = y0 + py;
    const int gx = x0 + px;

    // ---- 9x9 depth neighborhood -> registers (static indices only) ----
    float nb[81];
#pragma unroll
    for (int dy = 0; dy < 9; ++dy)
#pragma unroll
        for (int dx = 0; dx < 9; ++dx)
            nb[dy * 9 + dx] = sD[py + dy][px + dx];

    // kernel weights (uniform -> scalar loads)
    float wv[25];
#pragma unroll
    for (int j = 0; j < 25; ++j) wv[j] = wker[j];

    // effective weights: conv zero-pads jump in p-space -> anchor-OOB taps drop out
    bool vy[5], vx[5];
#pragma unroll
    for (int d = 0; d < 5; ++d) {
        vy[d] = ((unsigned)(gy + d - 2) < (unsigned)HH);
        vx[d] = ((unsigned)(gx + d - 2) < (unsigned)WW);
    }
    float wje[25];
#pragma unroll
    for (int j = 0; j < 25; ++j) {
        const int jy = j / 5, jx = j % 5;
        float w = vx[jx] ? wv[j] : 0.0f;
        wje[j] = vy[jy] ? w : 0.0f;
    }

    float dist[25];
#pragma unroll
    for (int k = 0; k < 25; ++k) dist[k] = 0.0f;
    // dist[12] (k-offset (0,0)) is exactly +0.0: |D-D| = 0 each term -> skip.

#pragma unroll
    for (int j = 0; j < 25; ++j) {
        const int jy = j / 5, jx = j % 5;
        const float Dq = nb[(2 + jy) * 9 + (2 + jx)];
        const float wj = wje[j];
#pragma unroll
        for (int k = 0; k < 25; ++k) {
            if (k == 12) continue;
            const int ky = k / 5, kx = k % 5;
            const float diff = nb[(jy + ky) * 9 + (jx + kx)] - Dq;
            dist[k] = fmaf(wj, fabsf(diff), dist[k]);
        }
    }

    // ---- stable top-5 smallest (strict <, ties -> lower k, = lax.top_k) ----
    int labs[5];
#pragma unroll
    for (int r = 0; r < 5; ++r) {
        float best = 3.4e38f;
        int bi = 0;
#pragma unroll
        for (int k = 0; k < 25; ++k) {
            if (dist[k] < best) { best = dist[k]; bi = k; }
        }
        int ky = (bi * 205) >> 10;       // bi / 5 for bi in [0,25)
        int kx = bi - ky * 5;
        int lv = (best > 1.0f) ? NC : sL[py + ky][px + kx];
        labs[r] = lv;
        if (r < 4) {
#pragma unroll
            for (int k = 0; k < 25; ++k) {
                if (k == bi) dist[k] = 3.4e38f;
            }
        }
    }

    // ---- majority vote over 5 labels; argmax ties -> lowest class index ----
    int bestLab = 0, bestCnt = 0;
#pragma unroll
    for (int i = 0; i < 5; ++i) {
        const int li = labs[i];
        int c = 0;
#pragma unroll
        for (int j = 0; j < 5; ++j) c += (labs[j] == li) ? 1 : 0;
        if (li < NC && (c > bestCnt || (c == bestCnt && li < bestLab))) {
            bestCnt = c;
            bestLab = li;
        }
    }

    out[(size_t)b * (HH * WW) + (size_t)gy * WW + gx] = bestLab;
}

extern "C" void kernel_launch(void* const* d_in, const int* in_sizes, int n_in,
                              void* d_out, int out_size, void* d_ws, size_t ws_size,
                              hipStream_t stream) {
    const float* depth = (const float*)d_in[0];
    const int*   label = (const int*)d_in[1];
    const float* wker  = (const float*)d_in[2];
    int*         out   = (int*)d_out;

    dim3 grid(WW / 64, HH / 4, BB);
    knn_refine<<<grid, dim3(256), 0, stream>>>(depth, label, wker, out);
}